// Round 19
// baseline (597.838 us; speedup 1.0000x reference)
//
#include <hip/hip_runtime.h>

typedef _Float16 half8  __attribute__((ext_vector_type(8)));
typedef _Float16 half4_t __attribute__((ext_vector_type(4)));
typedef __fp16   fp16x2 __attribute__((ext_vector_type(2)));
typedef float    f32x4  __attribute__((ext_vector_type(4)));

union PKU  { fp16x2 h; int i; };
union PK2  { fp16x2 h[2]; int i[2]; half4_t h4; };

__device__ __forceinline__ half4_t mk4(int a, int b) {
  PK2 u; u.i[0] = a; u.i[1] = b; return u.h4;
}

// swizzled token-LDS index (halves). XOR bits are multiples of 8 halves (16 B),
// so 16B ds_read_b128 chunks stay contiguous; 4-half runs (8B) also survive.
__device__ __forceinline__ int tokIdx(int r, int c) { return r*256 + (c ^ ((r & 7) << 3)); }

// ---- fp32 -> fp16 weight conversion (vectorized: 8 elems/thread) ----
__global__ void __launch_bounds__(256)
wconv_kernel(const float* __restrict__ wq, const float* __restrict__ wp,
             _Float16* __restrict__ o)
{
  const int i = (blockIdx.x * 256 + threadIdx.x) * 8;   // grid covers 262144 elems
  const float4 a = *(const float4*)((i < 768*256 ? wq + i : wp + (i - 768*256)));
  const float4 b = *(const float4*)((i < 768*256 ? wq + i + 4 : wp + (i - 768*256) + 4));
  half8 h;
  h[0] = (_Float16)a.x; h[1] = (_Float16)a.y; h[2] = (_Float16)a.z; h[3] = (_Float16)a.w;
  h[4] = (_Float16)b.x; h[5] = (_Float16)b.y; h[6] = (_Float16)b.z; h[7] = (_Float16)b.w;
  *(half8*)(o + i) = h;
}

// 256 threads = 4 waves; 2 heads per wave; one 8x8 window per block.
// (256,3): unified budget ~170/wave (R12/R18: 84 arch + 64 acc peak, no spill).
// R19: head-INTERLEAVED schedule — h1's QK hoisted between h0's softmax and
// h0's V/PV, reusing the same register arrays (h0's qtp/kcp are dead by then).
// Zero extra state; gives the scheduler an MFMA/LDS phase adjacent to the
// VALU/shuffle-bound softmax chain.
__global__ void __launch_bounds__(256, 3)
attn_kernel(const float* __restrict__ x,
            const float* __restrict__ b_qkv,
            const float* __restrict__ b_proj,
            const _Float16* __restrict__ w16,
            float* __restrict__ out)
{
  __shared__ __align__(16) _Float16 tok[64*256];   // 32 KB total LDS

  const int tid  = threadIdx.x;
  const int lane = tid & 63;
  const int w    = tid >> 6;
  const int l15  = lane & 15;
  const int g    = lane >> 4;

  const int wid = blockIdx.x;
  const int b   = wid / (24*24);
  const int wh  = (wid / 24) % 24;
  const int ww  = wid % 24;
  const long long base = (((long long)b*192 + wh*8)*192 + ww*8)*256;

  // ------- stage tokens -> LDS fp16 (swizzled); 2 rows/iter, 16B/lane writes -------
  {
    const int l31 = lane & 31;
    const int rh  = lane >> 5;          // 0/1: which row of the pair
#pragma unroll
    for (int i = 0; i < 8; ++i) {
      const int tk = w*16 + i*2 + rh;
      const float* src = x + base + ((tk >> 3)*192 + (tk & 7))*256 + l31*8;
      const f32x4 v0 = *(const f32x4*)(src);
      const f32x4 v1 = *(const f32x4*)(src + 4);
      half8 h;
      h[0] = (_Float16)v0[0]; h[1] = (_Float16)v0[1];
      h[2] = (_Float16)v0[2]; h[3] = (_Float16)v0[3];
      h[4] = (_Float16)v1[0]; h[5] = (_Float16)v1[1];
      h[6] = (_Float16)v1[2]; h[7] = (_Float16)v1[3];
      *(half8*)(tok + tk*256 + ((l31*8) ^ ((tk & 7) << 3))) = h;
    }
  }
  __syncthreads();

  const _Float16* wqkv16  = w16;
  const _Float16* wproj16 = w16 + 768*256;

  // 1/sqrt(32) * log2(e): softmax uses exp2 directly (v_exp_f32 is 2^x)
  const float ALPHA2 = 0.25503487237560903f;

  // shared register arrays, time-multiplexed between the two heads
  int qtp[2][4][2], kcp[2][4][2];   // QK packs: h0's die at S(h0); h1 reuses
  int pk[4][4][2];                  // P packs: h0's die at PV(h0); h1 reuses
  float rv[4];
  int vpk[4][2][2];
  int ohp[2][2][4][2];              // packed O^T fragments, both heads

  // -------- QK phase: merged [Q^T;K^T] = [Wq;Wk] * X^T, bias-init, pack --------
  auto QK = [&](int hd) {
    f32x4 qa[2][4], kc[2][4];
#pragma unroll
    for (int mi = 0; mi < 2; ++mi) {
      const f32x4 bqv = *(const f32x4*)(b_qkv + hd*32 + mi*16 + g*4);
      const f32x4 bkv = *(const f32x4*)(b_qkv + 256 + hd*32 + mi*16 + g*4);
#pragma unroll
      for (int ni = 0; ni < 4; ++ni) { qa[mi][ni] = bqv; kc[mi][ni] = bkv; }
    }
#pragma unroll
    for (int kk = 0; kk < 8; ++kk) {
      half8 bt[4], awq[2], awk[2];
#pragma unroll
      for (int ni = 0; ni < 4; ++ni)
        bt[ni] = *(const half8*)(tok + tokIdx(ni*16 + l15, kk*32 + g*8));
#pragma unroll
      for (int mi = 0; mi < 2; ++mi) {
        awq[mi] = *(const half8*)(wqkv16 + (      hd*32 + mi*16 + l15)*256 + kk*32 + g*8);
        awk[mi] = *(const half8*)(wqkv16 + (256 + hd*32 + mi*16 + l15)*256 + kk*32 + g*8);
      }
      __builtin_amdgcn_s_setprio(1);
#pragma unroll
      for (int mi = 0; mi < 2; ++mi)
#pragma unroll
        for (int ni = 0; ni < 4; ++ni) {
          qa[mi][ni] = __builtin_amdgcn_mfma_f32_16x16x32_f16(awq[mi], bt[ni], qa[mi][ni], 0, 0, 0);
          kc[mi][ni] = __builtin_amdgcn_mfma_f32_16x16x32_f16(awk[mi], bt[ni], kc[mi][ni], 0, 0, 0);
        }
      __builtin_amdgcn_s_setprio(0);
    }
#pragma unroll
    for (int mi = 0; mi < 2; ++mi)
#pragma unroll
      for (int ni = 0; ni < 4; ++ni) {
        PKU q0, q1, k0, k1;
        q0.h = __builtin_amdgcn_cvt_pkrtz(qa[mi][ni][0]*ALPHA2, qa[mi][ni][1]*ALPHA2);
        q1.h = __builtin_amdgcn_cvt_pkrtz(qa[mi][ni][2]*ALPHA2, qa[mi][ni][3]*ALPHA2);
        k0.h = __builtin_amdgcn_cvt_pkrtz(kc[mi][ni][0], kc[mi][ni][1]);
        k1.h = __builtin_amdgcn_cvt_pkrtz(kc[mi][ni][2], kc[mi][ni][3]);
        qtp[mi][ni][0] = q0.i; qtp[mi][ni][1] = q1.i;
        kcp[mi][ni][0] = k0.i; kcp[mi][ni][1] = k1.i;
      }
  };

  // -------- S^T = K * Q^T via K=16 MFMA (ni-pairs, acc 32) + softmax --------
  auto SSM = [&]() {
#pragma unroll
    for (int pr = 0; pr < 2; ++pr) {
      f32x4 s[4][2];
#pragma unroll
      for (int MI = 0; MI < 4; ++MI)
#pragma unroll
        for (int nj = 0; nj < 2; ++nj) s[MI][nj] = (f32x4)0.0f;
      __builtin_amdgcn_s_setprio(1);
#pragma unroll
      for (int kk2 = 0; kk2 < 2; ++kk2)
#pragma unroll
        for (int nj = 0; nj < 2; ++nj) {
          const int ni = pr*2 + nj;
          const half4_t qb = mk4(qtp[kk2][ni][0], qtp[kk2][ni][1]);
#pragma unroll
          for (int MI = 0; MI < 4; ++MI)
            s[MI][nj] = __builtin_amdgcn_mfma_f32_16x16x16f16(
                mk4(kcp[kk2][MI][0], kcp[kk2][MI][1]), qb, s[MI][nj], 0, 0, 0);
        }
      __builtin_amdgcn_s_setprio(0);

#pragma unroll
      for (int nj = 0; nj < 2; ++nj) {
        const int ni = pr*2 + nj;
        float mm[4];
#pragma unroll
        for (int MI = 0; MI < 4; ++MI)
          mm[MI] = fmaxf(fmaxf(fmaxf(s[MI][nj][0], s[MI][nj][1]), s[MI][nj][2]), s[MI][nj][3]);
        float m = fmaxf(fmaxf(fmaxf(mm[0], mm[1]), mm[2]), mm[3]);
        m = fmaxf(m, __shfl_xor(m, 16, 64));
        m = fmaxf(m, __shfl_xor(m, 32, 64));
        float ss[4];
#pragma unroll
        for (int MI = 0; MI < 4; ++MI) {
#pragma unroll
          for (int r = 0; r < 4; ++r) s[MI][nj][r] = __builtin_amdgcn_exp2f(s[MI][nj][r] - m);
          ss[MI] = (s[MI][nj][0] + s[MI][nj][1]) + (s[MI][nj][2] + s[MI][nj][3]);
        }
        float sum = (ss[0] + ss[1]) + (ss[2] + ss[3]);
        sum += __shfl_xor(sum, 16, 64);
        sum += __shfl_xor(sum, 32, 64);
        rv[ni] = __builtin_amdgcn_rcpf(sum);
#pragma unroll
        for (int MI = 0; MI < 4; ++MI) {
          PKU u0, u1;
          u0.h = __builtin_amdgcn_cvt_pkrtz(s[MI][nj][0], s[MI][nj][1]);
          u1.h = __builtin_amdgcn_cvt_pkrtz(s[MI][nj][2], s[MI][nj][3]);
          pk[MI][ni][0] = u0.i;
          pk[MI][ni][1] = u1.i;
        }
      }
    }
  };

  // -------- V = X * Wv^T (acc 32, bias-init), pack --------
  auto VG = [&](int hd) {
    f32x4 vv[4][2];
#pragma unroll
    for (int ni = 0; ni < 2; ++ni) {
      const float bv = b_qkv[512 + hd*32 + ni*16 + l15];
#pragma unroll
      for (int mi = 0; mi < 4; ++mi) vv[mi][ni] = (f32x4)bv;
    }
#pragma unroll
    for (int kk = 0; kk < 8; ++kk) {
      half8 bt[4], wv[2];
#pragma unroll
      for (int mi = 0; mi < 4; ++mi)
        bt[mi] = *(const half8*)(tok + tokIdx(mi*16 + l15, kk*32 + g*8));
#pragma unroll
      for (int ni = 0; ni < 2; ++ni)
        wv[ni] = *(const half8*)(wqkv16 + (512 + hd*32 + ni*16 + l15)*256 + kk*32 + g*8);
      __builtin_amdgcn_s_setprio(1);
#pragma unroll
      for (int mi = 0; mi < 4; ++mi)
#pragma unroll
        for (int ni = 0; ni < 2; ++ni)
          vv[mi][ni] = __builtin_amdgcn_mfma_f32_16x16x32_f16(bt[mi], wv[ni], vv[mi][ni], 0, 0, 0);
      __builtin_amdgcn_s_setprio(0);
    }
#pragma unroll
    for (int ni = 0; ni < 2; ++ni)
#pragma unroll
      for (int mi = 0; mi < 4; ++mi) {
        PKU u0, u1;
        u0.h = __builtin_amdgcn_cvt_pkrtz(vv[mi][ni][0], vv[mi][ni][1]);
        u1.h = __builtin_amdgcn_cvt_pkrtz(vv[mi][ni][2], vv[mi][ni][3]);
        vpk[mi][ni][0] = u0.i;
        vpk[mi][ni][1] = u1.i;
      }
  };

  // -------- O^T = V^T * P^T via K=16 MFMA (acc 32), pack into ohp[hi] --------
  auto PV = [&](int hi) {
    f32x4 oh[2][4];
#pragma unroll
    for (int MI = 0; MI < 2; ++MI)
#pragma unroll
      for (int ni = 0; ni < 4; ++ni) oh[MI][ni] = (f32x4)0.0f;
    __builtin_amdgcn_s_setprio(1);
#pragma unroll
    for (int kk2 = 0; kk2 < 4; ++kk2)
#pragma unroll
      for (int ni = 0; ni < 4; ++ni) {
        const half4_t pb = mk4(pk[kk2][ni][0], pk[kk2][ni][1]);
#pragma unroll
        for (int MI = 0; MI < 2; ++MI)
          oh[MI][ni] = __builtin_amdgcn_mfma_f32_16x16x16f16(
              mk4(vpk[kk2][MI][0], vpk[kk2][MI][1]), pb, oh[MI][ni], 0, 0, 0);
      }
    __builtin_amdgcn_s_setprio(0);
#pragma unroll
    for (int MI = 0; MI < 2; ++MI)
#pragma unroll
      for (int ni = 0; ni < 4; ++ni) {
        PK2 u;
        u.h[0] = __builtin_amdgcn_cvt_pkrtz(oh[MI][ni][0] * rv[ni], oh[MI][ni][1] * rv[ni]);
        u.h[1] = __builtin_amdgcn_cvt_pkrtz(oh[MI][ni][2] * rv[ni], oh[MI][ni][3] * rv[ni]);
        ohp[hi][MI][ni][0] = u.i[0];
        ohp[hi][MI][ni][1] = u.i[1];
      }
  };

  // ---- interleaved schedule: h1's QK fills h0's softmax/PV stalls ----
  const int h0 = 2*w, h1 = 2*w + 1;
  QK(h0);
  SSM();        // h0 softmax -> pk, rv (qtp/kcp now dead)
  QK(h1);       // hoisted: overwrites qtp/kcp with h1; MFMA/LDS overlaps sm VALU
  VG(h0);
  PV(0);        // consumes pk/rv (h0)
  SSM();        // h1 (qtp/kcp = h1) -> pk, rv
  VG(h1);
  PV(1);

  __syncthreads();   // all waves done reading tok

  // ---------------- write attention output into LDS (aliases tok), b64 ----------------
#pragma unroll
  for (int hi = 0; hi < 2; ++hi) {
    const int hd = 2*w + hi;
#pragma unroll
    for (int MI = 0; MI < 2; ++MI)
#pragma unroll
      for (int ni = 0; ni < 4; ++ni) {
        PK2 u;
        u.i[0] = ohp[hi][MI][ni][0];
        u.i[1] = ohp[hi][MI][ni][1];
        *(half4_t*)(tok + tokIdx(ni*16 + l15, hd*32 + MI*16 + g*4)) = u.h4;
      }
  }
  __syncthreads();

  // ---------------- proj: out = AO * Wp^T + bp  (M=64, N=64/wave, K=256); bias-init ----------------
  f32x4 pa[4][4];
#pragma unroll
  for (int ni = 0; ni < 4; ++ni) {
    const float bb = b_proj[w*64 + ni*16 + l15];
#pragma unroll
    for (int mi = 0; mi < 4; ++mi) pa[mi][ni] = (f32x4)bb;
  }

#pragma unroll
  for (int kk = 0; kk < 8; ++kk) {
    half8 af[4], bf[4];
#pragma unroll
    for (int mi = 0; mi < 4; ++mi)
      af[mi] = *(const half8*)(tok + tokIdx(mi*16 + l15, kk*32 + g*8));
#pragma unroll
    for (int ni = 0; ni < 4; ++ni)
      bf[ni] = *(const half8*)(wproj16 + (w*64 + ni*16 + l15)*256 + kk*32 + g*8);
    __builtin_amdgcn_s_setprio(1);
#pragma unroll
    for (int mi = 0; mi < 4; ++mi)
#pragma unroll
      for (int ni = 0; ni < 4; ++ni)
        pa[mi][ni] = __builtin_amdgcn_mfma_f32_16x16x32_f16(af[mi], bf[ni], pa[mi][ni], 0, 0, 0);
    __builtin_amdgcn_s_setprio(0);
  }

  // ---------------- staged output: 2 passes of 32 rows; 1KB-contiguous row stores ----------------
  float* tokF = (float*)tok;   // [32][256] f32, swizzled (aliases tok)
#pragma unroll
  for (int p = 0; p < 2; ++p) {
    __syncthreads();   // p=0: proj reads of tok done; p=1: pass-0 reads done
#pragma unroll
    for (int mh = 0; mh < 2; ++mh) {
      const int mi = 2*p + mh;
#pragma unroll
      for (int ni = 0; ni < 4; ++ni)
#pragma unroll
        for (int r = 0; r < 4; ++r) {
          const int tr = mh*16 + g*4 + r;
          tokF[tr*256 + ((w*64 + ni*16 + l15) ^ ((tr & 7) << 2))] = pa[mi][ni][r];
        }
    }
    __syncthreads();
    // each wave stores 8 full token rows: 64 lanes x 16B = 1024B contiguous per store
#pragma unroll
    for (int i = 0; i < 8; ++i) {
      const int tr = w*8 + i;
      const int t  = p*32 + tr;
      const long long rowbase = base + ((long long)(t >> 3)*192 + (t & 7))*256;
      const f32x4 v4 = *(const f32x4*)(tokF + tr*256 + ((lane*4) ^ ((tr & 7) << 2)));
      *(f32x4*)(out + rowbase + lane*4) = v4;
    }
  }
}

extern "C" void kernel_launch(void* const* d_in, const int* in_sizes, int n_in,
                              void* d_out, int out_size, void* d_ws, size_t ws_size,
                              hipStream_t stream) {
  const float* x      = (const float*)d_in[0];
  const float* w_qkv  = (const float*)d_in[1];
  const float* b_qkv  = (const float*)d_in[2];
  const float* w_proj = (const float*)d_in[3];
  const float* b_proj = (const float*)d_in[4];
  float* out = (float*)d_out;
  _Float16* w16 = (_Float16*)d_ws;

  wconv_kernel<<<128, 256, 0, stream>>>(w_qkv, w_proj, w16);
  attn_kernel<<<4608, 256, 0, stream>>>(x, b_qkv, b_proj, w16, out);
}

// Round 20
// 335.105 us; speedup vs baseline: 1.7840x; 1.7840x over previous
//
#include <hip/hip_runtime.h>

typedef _Float16 half8  __attribute__((ext_vector_type(8)));
typedef _Float16 half4_t __attribute__((ext_vector_type(4)));
typedef __fp16   fp16x2 __attribute__((ext_vector_type(2)));
typedef float    f32x4  __attribute__((ext_vector_type(4)));

union PKU  { fp16x2 h; int i; };
union PK2  { fp16x2 h[2]; int i[2]; half4_t h4; };

__device__ __forceinline__ half4_t mk4(int a, int b) {
  PK2 u; u.i[0] = a; u.i[1] = b; return u.h4;
}

// swizzled token-LDS index (halves). XOR bits are multiples of 8 halves (16 B),
// so 16B ds_read_b128 chunks stay contiguous; 4-half runs (8B) also survive.
__device__ __forceinline__ int tokIdx(int r, int c) { return r*256 + (c ^ ((r & 7) << 3)); }

// ---- fp32 -> fp16 weight conversion (vectorized: 8 elems/thread) ----
__global__ void __launch_bounds__(256)
wconv_kernel(const float* __restrict__ wq, const float* __restrict__ wp,
             _Float16* __restrict__ o)
{
  const int i = (blockIdx.x * 256 + threadIdx.x) * 8;   // grid covers 262144 elems
  const float4 a = *(const float4*)((i < 768*256 ? wq + i : wp + (i - 768*256)));
  const float4 b = *(const float4*)((i < 768*256 ? wq + i + 4 : wp + (i - 768*256) + 4));
  half8 h;
  h[0] = (_Float16)a.x; h[1] = (_Float16)a.y; h[2] = (_Float16)a.z; h[3] = (_Float16)a.w;
  h[4] = (_Float16)b.x; h[5] = (_Float16)b.y; h[6] = (_Float16)b.z; h[7] = (_Float16)b.w;
  *(half8*)(o + i) = h;
}

// 256 threads = 4 waves; 2 heads per wave (sequential); one 8x8 window per block.
// (256,3): unified budget ~170/wave, arch cap ~85 (measured: 84 arch + 64 acc
// peak, no spill, FETCH/WRITE at algorithmic ideal). CHAMPION configuration:
// - fp16 MFMA everywhere (no fp32 MFMA on CDNA4); absmax 0.0078 << 0.03125
// - merged QK GEMM (shared tok fragments), bias via MFMA C-in init
// - S and PV consume C-fragments DIRECTLY via K=16 MFMAs (operand k-layout
//   g*4+j == C-frag row layout) — zero cross-lane transposes
// - softmax: exp2 with log2e folded into Q-scale, rcp, max3-friendly reduce
// - staged output through LDS -> full 1KB-row stores (write amplification 1.0)
// Structural escapes (2-window pipeline, 4 waves/SIMD, phase overlap, head
// interleave) all spill: any extra concurrent phase needs ~32 live ints more
// than the (256,3) register bucket holds. This is the practical plateau.
__global__ void __launch_bounds__(256, 3)
attn_kernel(const float* __restrict__ x,
            const float* __restrict__ b_qkv,
            const float* __restrict__ b_proj,
            const _Float16* __restrict__ w16,
            float* __restrict__ out)
{
  __shared__ __align__(16) _Float16 tok[64*256];   // 32 KB total LDS

  const int tid  = threadIdx.x;
  const int lane = tid & 63;
  const int w    = tid >> 6;
  const int l15  = lane & 15;
  const int g    = lane >> 4;

  const int wid = blockIdx.x;
  const int b   = wid / (24*24);
  const int wh  = (wid / 24) % 24;
  const int ww  = wid % 24;
  const long long base = (((long long)b*192 + wh*8)*192 + ww*8)*256;

  // ------- stage tokens -> LDS fp16 (swizzled); 2 rows/iter, 16B/lane writes -------
  {
    const int l31 = lane & 31;
    const int rh  = lane >> 5;          // 0/1: which row of the pair
#pragma unroll
    for (int i = 0; i < 8; ++i) {
      const int tk = w*16 + i*2 + rh;
      const float* src = x + base + ((tk >> 3)*192 + (tk & 7))*256 + l31*8;
      const f32x4 v0 = *(const f32x4*)(src);
      const f32x4 v1 = *(const f32x4*)(src + 4);
      half8 h;
      h[0] = (_Float16)v0[0]; h[1] = (_Float16)v0[1];
      h[2] = (_Float16)v0[2]; h[3] = (_Float16)v0[3];
      h[4] = (_Float16)v1[0]; h[5] = (_Float16)v1[1];
      h[6] = (_Float16)v1[2]; h[7] = (_Float16)v1[3];
      *(half8*)(tok + tk*256 + ((l31*8) ^ ((tk & 7) << 3))) = h;
    }
  }
  __syncthreads();

  const _Float16* wqkv16  = w16;
  const _Float16* wproj16 = w16 + 768*256;

  // 1/sqrt(32) * log2(e): softmax uses exp2 directly (v_exp_f32 is 2^x)
  const float ALPHA2 = 0.25503487237560903f;

  int ohp[2][2][4][2];   // packed fp16 O^T fragments, both heads (32 ints)

#pragma unroll
  for (int hi = 0; hi < 2; ++hi) {
    const int hd = 2*w + hi;

    // -------- merged [Q^T;K^T] = [Wq;Wk] * X^T (2x M=32, N=64, K=256) --------
    // bias via accumulator-init (MFMA C-in); one bt read set for both.
    int qtp[2][4][2], kcp[2][4][2];
    {
      f32x4 qa[2][4], kc[2][4];
#pragma unroll
      for (int mi = 0; mi < 2; ++mi) {
        const f32x4 bqv = *(const f32x4*)(b_qkv + hd*32 + mi*16 + g*4);
        const f32x4 bkv = *(const f32x4*)(b_qkv + 256 + hd*32 + mi*16 + g*4);
#pragma unroll
        for (int ni = 0; ni < 4; ++ni) { qa[mi][ni] = bqv; kc[mi][ni] = bkv; }
      }
#pragma unroll
      for (int kk = 0; kk < 8; ++kk) {
        half8 bt[4], awq[2], awk[2];
#pragma unroll
        for (int ni = 0; ni < 4; ++ni)
          bt[ni] = *(const half8*)(tok + tokIdx(ni*16 + l15, kk*32 + g*8));
#pragma unroll
        for (int mi = 0; mi < 2; ++mi) {
          awq[mi] = *(const half8*)(wqkv16 + (      hd*32 + mi*16 + l15)*256 + kk*32 + g*8);
          awk[mi] = *(const half8*)(wqkv16 + (256 + hd*32 + mi*16 + l15)*256 + kk*32 + g*8);
        }
        __builtin_amdgcn_s_setprio(1);
#pragma unroll
        for (int mi = 0; mi < 2; ++mi)
#pragma unroll
          for (int ni = 0; ni < 4; ++ni) {
            qa[mi][ni] = __builtin_amdgcn_mfma_f32_16x16x32_f16(awq[mi], bt[ni], qa[mi][ni], 0, 0, 0);
            kc[mi][ni] = __builtin_amdgcn_mfma_f32_16x16x32_f16(awk[mi], bt[ni], kc[mi][ni], 0, 0, 0);
          }
        __builtin_amdgcn_s_setprio(0);
      }
      // pack (Q scaled by ALPHA2; K plain)
#pragma unroll
      for (int mi = 0; mi < 2; ++mi)
#pragma unroll
        for (int ni = 0; ni < 4; ++ni) {
          PKU q0, q1, k0, k1;
          q0.h = __builtin_amdgcn_cvt_pkrtz(qa[mi][ni][0]*ALPHA2, qa[mi][ni][1]*ALPHA2);
          q1.h = __builtin_amdgcn_cvt_pkrtz(qa[mi][ni][2]*ALPHA2, qa[mi][ni][3]*ALPHA2);
          k0.h = __builtin_amdgcn_cvt_pkrtz(kc[mi][ni][0], kc[mi][ni][1]);
          k1.h = __builtin_amdgcn_cvt_pkrtz(kc[mi][ni][2], kc[mi][ni][3]);
          qtp[mi][ni][0] = q0.i; qtp[mi][ni][1] = q1.i;
          kcp[mi][ni][0] = k0.i; kcp[mi][ni][1] = k1.i;
        }
    }

    // -------- S^T = K * Q^T via K=16 MFMA, ni-PAIRS (acc peak 32) + softmax --------
    int pk[4][4][2];
    float rv[4];
#pragma unroll
    for (int pr = 0; pr < 2; ++pr) {
      f32x4 s[4][2];
#pragma unroll
      for (int MI = 0; MI < 4; ++MI)
#pragma unroll
        for (int nj = 0; nj < 2; ++nj) s[MI][nj] = (f32x4)0.0f;
      __builtin_amdgcn_s_setprio(1);
#pragma unroll
      for (int kk2 = 0; kk2 < 2; ++kk2)
#pragma unroll
        for (int nj = 0; nj < 2; ++nj) {
          const int ni = pr*2 + nj;
          const half4_t qb = mk4(qtp[kk2][ni][0], qtp[kk2][ni][1]);
#pragma unroll
          for (int MI = 0; MI < 4; ++MI)
            s[MI][nj] = __builtin_amdgcn_mfma_f32_16x16x16f16(
                mk4(kcp[kk2][MI][0], kcp[kk2][MI][1]), qb, s[MI][nj], 0, 0, 0);
        }
      __builtin_amdgcn_s_setprio(0);

#pragma unroll
      for (int nj = 0; nj < 2; ++nj) {
        const int ni = pr*2 + nj;
        // max-reduce with left-nested chains (clang fuses v_max3_f32)
        float mm[4];
#pragma unroll
        for (int MI = 0; MI < 4; ++MI)
          mm[MI] = fmaxf(fmaxf(fmaxf(s[MI][nj][0], s[MI][nj][1]), s[MI][nj][2]), s[MI][nj][3]);
        float m = fmaxf(fmaxf(fmaxf(mm[0], mm[1]), mm[2]), mm[3]);
        m = fmaxf(m, __shfl_xor(m, 16, 64));
        m = fmaxf(m, __shfl_xor(m, 32, 64));
        // exp2 (direct v_exp_f32) + tree sum
        float ss[4];
#pragma unroll
        for (int MI = 0; MI < 4; ++MI) {
#pragma unroll
          for (int r = 0; r < 4; ++r) s[MI][nj][r] = __builtin_amdgcn_exp2f(s[MI][nj][r] - m);
          ss[MI] = (s[MI][nj][0] + s[MI][nj][1]) + (s[MI][nj][2] + s[MI][nj][3]);
        }
        float sum = (ss[0] + ss[1]) + (ss[2] + ss[3]);
        sum += __shfl_xor(sum, 16, 64);
        sum += __shfl_xor(sum, 32, 64);
        rv[ni] = __builtin_amdgcn_rcpf(sum);
#pragma unroll
        for (int MI = 0; MI < 4; ++MI) {
          PKU u0, u1;
          u0.h = __builtin_amdgcn_cvt_pkrtz(s[MI][nj][0], s[MI][nj][1]);
          u1.h = __builtin_amdgcn_cvt_pkrtz(s[MI][nj][2], s[MI][nj][3]);
          pk[MI][ni][0] = u0.i;
          pk[MI][ni][1] = u1.i;
        }
      }
    }

    // -------- V = X * Wv^T  (M=64 tok, N=32 d, K=256); acc 32, bias-init --------
    int vpk[4][2][2];
    {
      f32x4 vv[4][2];
#pragma unroll
      for (int ni = 0; ni < 2; ++ni) {
        const float bv = b_qkv[512 + hd*32 + ni*16 + l15];
#pragma unroll
        for (int mi = 0; mi < 4; ++mi) vv[mi][ni] = (f32x4)bv;
      }
#pragma unroll
      for (int kk = 0; kk < 8; ++kk) {
        half8 bt[4], wv[2];
#pragma unroll
        for (int mi = 0; mi < 4; ++mi)
          bt[mi] = *(const half8*)(tok + tokIdx(mi*16 + l15, kk*32 + g*8));
#pragma unroll
        for (int ni = 0; ni < 2; ++ni)
          wv[ni] = *(const half8*)(wqkv16 + (512 + hd*32 + ni*16 + l15)*256 + kk*32 + g*8);
        __builtin_amdgcn_s_setprio(1);
#pragma unroll
        for (int mi = 0; mi < 4; ++mi)
#pragma unroll
          for (int ni = 0; ni < 2; ++ni)
            vv[mi][ni] = __builtin_amdgcn_mfma_f32_16x16x32_f16(bt[mi], wv[ni], vv[mi][ni], 0, 0, 0);
        __builtin_amdgcn_s_setprio(0);
      }
#pragma unroll
      for (int ni = 0; ni < 2; ++ni)
#pragma unroll
        for (int mi = 0; mi < 4; ++mi) {
          PKU u0, u1;
          u0.h = __builtin_amdgcn_cvt_pkrtz(vv[mi][ni][0], vv[mi][ni][1]);
          u1.h = __builtin_amdgcn_cvt_pkrtz(vv[mi][ni][2], vv[mi][ni][3]);
          vpk[mi][ni][0] = u0.i;
          vpk[mi][ni][1] = u1.i;
        }
    }

    // -------- O^T = V^T * P^T via K=16 MFMA (acc peak 32), pack immediately --------
    {
      f32x4 oh[2][4];
#pragma unroll
      for (int MI = 0; MI < 2; ++MI)
#pragma unroll
        for (int ni = 0; ni < 4; ++ni) oh[MI][ni] = (f32x4)0.0f;
      __builtin_amdgcn_s_setprio(1);
#pragma unroll
      for (int kk2 = 0; kk2 < 4; ++kk2)
#pragma unroll
        for (int ni = 0; ni < 4; ++ni) {
          const half4_t pb = mk4(pk[kk2][ni][0], pk[kk2][ni][1]);
#pragma unroll
          for (int MI = 0; MI < 2; ++MI)
            oh[MI][ni] = __builtin_amdgcn_mfma_f32_16x16x16f16(
                mk4(vpk[kk2][MI][0], vpk[kk2][MI][1]), pb, oh[MI][ni], 0, 0, 0);
        }
      __builtin_amdgcn_s_setprio(0);
#pragma unroll
      for (int MI = 0; MI < 2; ++MI)
#pragma unroll
        for (int ni = 0; ni < 4; ++ni) {
          PK2 u;
          u.h[0] = __builtin_amdgcn_cvt_pkrtz(oh[MI][ni][0] * rv[ni], oh[MI][ni][1] * rv[ni]);
          u.h[1] = __builtin_amdgcn_cvt_pkrtz(oh[MI][ni][2] * rv[ni], oh[MI][ni][3] * rv[ni]);
          ohp[hi][MI][ni][0] = u.i[0];
          ohp[hi][MI][ni][1] = u.i[1];
        }
    }
  }

  __syncthreads();   // all waves done reading tok

  // ---------------- write attention output into LDS (aliases tok), b64 ----------------
#pragma unroll
  for (int hi = 0; hi < 2; ++hi) {
    const int hd = 2*w + hi;
#pragma unroll
    for (int MI = 0; MI < 2; ++MI)
#pragma unroll
      for (int ni = 0; ni < 4; ++ni) {
        PK2 u;
        u.i[0] = ohp[hi][MI][ni][0];
        u.i[1] = ohp[hi][MI][ni][1];
        *(half4_t*)(tok + tokIdx(ni*16 + l15, hd*32 + MI*16 + g*4)) = u.h4;
      }
  }
  __syncthreads();

  // ---------------- proj: out = AO * Wp^T + bp  (M=64, N=64/wave, K=256); bias-init ----------------
  f32x4 pa[4][4];
#pragma unroll
  for (int ni = 0; ni < 4; ++ni) {
    const float bb = b_proj[w*64 + ni*16 + l15];
#pragma unroll
    for (int mi = 0; mi < 4; ++mi) pa[mi][ni] = (f32x4)bb;
  }

#pragma unroll
  for (int kk = 0; kk < 8; ++kk) {
    half8 af[4], bf[4];
#pragma unroll
    for (int mi = 0; mi < 4; ++mi)
      af[mi] = *(const half8*)(tok + tokIdx(mi*16 + l15, kk*32 + g*8));
#pragma unroll
    for (int ni = 0; ni < 4; ++ni)
      bf[ni] = *(const half8*)(wproj16 + (w*64 + ni*16 + l15)*256 + kk*32 + g*8);
    __builtin_amdgcn_s_setprio(1);
#pragma unroll
    for (int mi = 0; mi < 4; ++mi)
#pragma unroll
      for (int ni = 0; ni < 4; ++ni)
        pa[mi][ni] = __builtin_amdgcn_mfma_f32_16x16x32_f16(af[mi], bf[ni], pa[mi][ni], 0, 0, 0);
    __builtin_amdgcn_s_setprio(0);
  }

  // ---------------- staged output: 2 passes of 32 rows; 1KB-contiguous row stores ----------------
  float* tokF = (float*)tok;   // [32][256] f32, swizzled (aliases tok)
#pragma unroll
  for (int p = 0; p < 2; ++p) {
    __syncthreads();   // p=0: proj reads of tok done; p=1: pass-0 reads done
#pragma unroll
    for (int mh = 0; mh < 2; ++mh) {
      const int mi = 2*p + mh;
#pragma unroll
      for (int ni = 0; ni < 4; ++ni)
#pragma unroll
        for (int r = 0; r < 4; ++r) {
          const int tr = mh*16 + g*4 + r;
          tokF[tr*256 + ((w*64 + ni*16 + l15) ^ ((tr & 7) << 2))] = pa[mi][ni][r];
        }
    }
    __syncthreads();
    // each wave stores 8 full token rows: 64 lanes x 16B = 1024B contiguous per store
#pragma unroll
    for (int i = 0; i < 8; ++i) {
      const int tr = w*8 + i;
      const int t  = p*32 + tr;
      const long long rowbase = base + ((long long)(t >> 3)*192 + (t & 7))*256;
      const f32x4 v4 = *(const f32x4*)(tokF + tr*256 + ((lane*4) ^ ((tr & 7) << 2)));
      *(f32x4*)(out + rowbase + lane*4) = v4;
    }
  }
}

extern "C" void kernel_launch(void* const* d_in, const int* in_sizes, int n_in,
                              void* d_out, int out_size, void* d_ws, size_t ws_size,
                              hipStream_t stream) {
  const float* x      = (const float*)d_in[0];
  const float* w_qkv  = (const float*)d_in[1];
  const float* b_qkv  = (const float*)d_in[2];
  const float* w_proj = (const float*)d_in[3];
  const float* b_proj = (const float*)d_in[4];
  float* out = (float*)d_out;
  _Float16* w16 = (_Float16*)d_ws;

  wconv_kernel<<<128, 256, 0, stream>>>(w_qkv, w_proj, w16);
  attn_kernel<<<4608, 256, 0, stream>>>(x, b_qkv, b_proj, w16, out);
}